// Round 5
// baseline (573.474 us; speedup 1.0000x reference)
//
#include <hip/hip_runtime.h>

// 5-layer GRU (H=16), T=512; only rows with length==T matter (~2 of 512, a
// PREFIX since lengths sorted descending). proj0 precomputes layer-0 xg.
// R5: chain-bound fixes: (1) yprev rows register-prefetched one step ahead
// (LDS latency off the recurrence chain); (2) exp2 weight-folding + n-gate
// computed on r-lanes (both cross-lane swaps moved off-chain); (3) chunk=16.

constexpr int kB = 512, kT = 512, kD = 128, kH = 16, kL = 5, kC = 2, kG = 48;
constexpr int kChunk = 16, kNC = kT / kChunk, kThreads = 320;
constexpr int kPhases = kNC + 2 * (kL - 1);
constexpr int kYW = 64;   // padded Y row: all 64 lanes write, [16..63] is pad
constexpr float kLog2e = 1.4426950408889634f;

typedef unsigned uint2v __attribute__((ext_vector_type(2)));

__device__ __forceinline__ float rl(float v, int lane) {
    return __int_as_float(__builtin_amdgcn_readlane(__float_as_int(v), lane));
}

__device__ __forceinline__ float fexp2(float x) {
#if __has_builtin(__builtin_amdgcn_exp2f)
    return __builtin_amdgcn_exp2f(x);
#else
    return exp2f(x);
#endif
}

#if __has_builtin(__builtin_amdgcn_permlane32_swap) && __has_builtin(__builtin_amdgcn_permlane16_swap)
// Direction-agnostic partner select (absmax 0 across R2-R4 -> proven form).
__device__ __forceinline__ float sel_other(uint2v r, float self) {
    unsigned s = __float_as_uint(self);
    return __uint_as_float((r[0] == s) ? r[1] : r[0]);
}
__device__ __forceinline__ float xor32(float v) {
    uint2v r = __builtin_amdgcn_permlane32_swap(__float_as_uint(v), __float_as_uint(v), false, false);
    return sel_other(r, v);
}
__device__ __forceinline__ float xor16(float v) {
    uint2v r = __builtin_amdgcn_permlane16_swap(__float_as_uint(v), __float_as_uint(v), false, false);
    return sel_other(r, v);
}
#else
__device__ __forceinline__ float bperm_xor(float v, int xmask) {
    int lane = threadIdx.x & 63;
    return __int_as_float(__builtin_amdgcn_ds_bpermute((lane ^ xmask) * 4, __float_as_int(v)));
}
__device__ __forceinline__ float xor32(float v) { return bperm_xor(v, 32); }
__device__ __forceinline__ float xor16(float v) { return bperm_xor(v, 16); }
#endif

// One GRU step. Lane g owns gate-row g (r:0-15, z:16-31, n:32-47); h in lanes
// 0-15. Weights/xg pre-scaled: rows<32 by log2e, rows>=32 by 2*log2e, so
// sigmoid = rcp(1+exp2(-s)) and tanh needs no argument multiply.
// n is evaluated ON the r-lanes (hg/xg swapped across the 32 boundary early,
// off the critical chain), so no swap sits between sigmoid and tanh.
__device__ __forceinline__ float gru_step(float h, float xg,
                                          const float (&wreg)[kH], float bh) {
    float a0 = bh, a1 = 0.f, a2 = 0.f, a3 = 0.f;
    #pragma unroll
    for (int k = 0; k < 4; ++k) {
        a0 = fmaf(rl(h, k),      wreg[k],      a0);
        a1 = fmaf(rl(h, k + 4),  wreg[k + 4],  a1);
        a2 = fmaf(rl(h, k + 8),  wreg[k + 8],  a2);
        a3 = fmaf(rl(h, k + 12), wreg[k + 12], a3);
    }
    float xnb = xor32(xg);                    // lanes<16 get xn' (off-chain)
    float hg = (a0 + a1) + (a2 + a3);
    float hnb = xor32(hg);                    // lanes<16 get hn' (off-chain)
    float s = xg + hg;                        // log2e-scaled for r/z lanes
    float sig = __builtin_amdgcn_rcpf(1.0f + fexp2(-s));   // r:0-15, z:16-31
    float zb = xor16(sig);                    // lanes<16 get z (|| tanh chain)
    float narg = fmaf(sig, hnb, xnb);         // lanes<16: 2log2e*(xn + r*hn)
    float nv = fmaf(-2.0f, __builtin_amdgcn_rcpf(fexp2(narg) + 1.0f), 1.0f);
    return fmaf(zb, h - nv, nv);              // h' = n + z*(h-n), lanes 0-15
}

// Fused phase over one chunk: scan chunk c from xgr while preparing chunk
// c+1's xg in-place. PREP: 0 none, 1 global load (wave 0), 2 project from
// prev layer's Y with one-step register prefetch of the Y row.
template<bool SCAN, int PREP, bool WY>
__device__ __forceinline__ float phase_body(
    float h, float (&xgr)[kChunk], const float* __restrict__ gsrc,
    const float (*__restrict__ yprev)[kYW], float (*__restrict__ yout)[kYW],
    const float (&wreg)[kH], float bh, const float (&wih)[kH], float bi,
    int lane)
{
    float4 ra0, ra1, ra2, ra3;
    if (PREP == 2) {                           // prefetch row 0
        const float4* y4 = (const float4*)&yprev[0][0];
        ra0 = y4[0]; ra1 = y4[1]; ra2 = y4[2]; ra3 = y4[3];
    }
    #pragma unroll
    for (int tt = 0; tt < kChunk; ++tt) {
        float4 rb0 = ra0, rb1 = ra1, rb2 = ra2, rb3 = ra3;
        if (PREP == 2 && tt + 1 < kChunk) {    // issue next row's loads early
            const float4* y4 = (const float4*)&yprev[tt + 1][0];
            rb0 = y4[0]; rb1 = y4[1]; rb2 = y4[2]; rb3 = y4[3];
        }
        if (SCAN) {
            h = gru_step(h, xgr[tt], wreg, bh);
            if (WY) yout[tt][lane] = h;        // unconditional; pad absorbs 16-63
        }
        if (PREP == 1) {
            xgr[tt] = gsrc[(size_t)tt * kG];
        } else if (PREP == 2) {
            float p0 = bi, p1 = 0.f, p2 = 0.f, p3 = 0.f;   // dot uses regs (ra)
            p0 = fmaf(ra0.x, wih[0],  p0); p0 = fmaf(ra0.y, wih[1],  p0);
            p0 = fmaf(ra0.z, wih[2],  p0); p0 = fmaf(ra0.w, wih[3],  p0);
            p1 = fmaf(ra1.x, wih[4],  p1); p1 = fmaf(ra1.y, wih[5],  p1);
            p1 = fmaf(ra1.z, wih[6],  p1); p1 = fmaf(ra1.w, wih[7],  p1);
            p2 = fmaf(ra2.x, wih[8],  p2); p2 = fmaf(ra2.y, wih[9],  p2);
            p2 = fmaf(ra2.z, wih[10], p2); p2 = fmaf(ra2.w, wih[11], p2);
            p3 = fmaf(ra3.x, wih[12], p3); p3 = fmaf(ra3.y, wih[13], p3);
            p3 = fmaf(ra3.z, wih[14], p3); p3 = fmaf(ra3.w, wih[15], p3);
            xgr[tt] = (p0 + p1) + (p2 + p3);
            ra0 = rb0; ra1 = rb1; ra2 = rb2; ra3 = rb3;    // SSA-renamed away
        }
    }
    return h;
}

// -------- prologue: xg0[b][t][g] = scale(g) * (b_ih[g] + W_ih0[g,:].x) ------
extern "C" __global__ void __launch_bounds__(256, 1)
proj0(const float* __restrict__ x, const int* __restrict__ len,
      const float* __restrict__ Wih0, const float* __restrict__ bih,
      float* __restrict__ xg0, int qmax)
{
    const int b = blockIdx.x;
    if (b >= qmax || len[b] != kT) return;
    const int tid = threadIdx.x;
    #pragma unroll 4
    for (int i = 0; i < 96; ++i) {
        int item = tid + 256 * i;               // item = t*48+g
        int t = item / kG, g = item - t * kG;
        const float4* xr = (const float4*)(x + ((size_t)b * kT + t) * kD);
        const float4* wr = (const float4*)(Wih0 + (size_t)g * kD);
        float a0 = 0.f, a1 = 0.f, a2 = 0.f, a3 = 0.f;
        #pragma unroll 8
        for (int k = 0; k < kD / 4; ++k) {
            float4 xv = xr[k], wv = wr[k];
            a0 = fmaf(xv.x, wv.x, a0);
            a1 = fmaf(xv.y, wv.y, a1);
            a2 = fmaf(xv.z, wv.z, a2);
            a3 = fmaf(xv.w, wv.w, a3);
        }
        float sc = (g < 32) ? kLog2e : 2.0f * kLog2e;
        xg0[((size_t)b * kT + t) * kG + g] = sc * (bih[g] + ((a0 + a1) + (a2 + a3)));
    }
}

// Fallback (ws too small for this row): wave 0 computes one chunk from x.
__device__ void proj_chunk_wave0(const float* __restrict__ x,
                                 const float* __restrict__ Wih0,
                                 const float* __restrict__ bih,
                                 int b, int c, int lane, float (*__restrict__ XW0)[kG])
{
    for (int i = 0; i < kChunk * kG / 64; ++i) {
        int item = lane + 64 * i;
        int t = item / kG, g = item - t * kG;
        const float4* xr = (const float4*)(x + ((size_t)b * kT + c * kChunk + t) * kD);
        const float4* wr = (const float4*)(Wih0 + (size_t)g * kD);
        float a0 = 0.f, a1 = 0.f, a2 = 0.f, a3 = 0.f;
        #pragma unroll 8
        for (int k = 0; k < kD / 4; ++k) {
            float4 xv = xr[k], wv = wr[k];
            a0 = fmaf(xv.x, wv.x, a0);
            a1 = fmaf(xv.y, wv.y, a1);
            a2 = fmaf(xv.z, wv.z, a2);
            a3 = fmaf(xv.w, wv.w, a3);
        }
        float sc = (g < 32) ? kLog2e : 2.0f * kLog2e;
        XW0[t][g] = sc * (bih[g] + ((a0 + a1) + (a2 + a3)));
    }
}

__device__ __forceinline__ void barrier_lgkm() {
    asm volatile("s_waitcnt lgkmcnt(0)" ::: "memory");
    __builtin_amdgcn_s_barrier();
}

extern "C" __global__ void __launch_bounds__(kThreads, 1)
gru_pipe4(const float* __restrict__ x, const int* __restrict__ len,
          const float* __restrict__ Wih0, const float* __restrict__ Wihr,
          const float* __restrict__ Whh, const float* __restrict__ bih,
          const float* __restrict__ bhh, const float* __restrict__ Wfc,
          const float* __restrict__ bfc, const float* __restrict__ xg0,
          float* __restrict__ out, int qmax)
{
    const int b = blockIdx.x;
    const int tid = threadIdx.x;

    if (len[b] != kT) {                 // uniform: output is just b_fc
        if (tid < kC) out[b * kC + tid] = bfc[tid];
        return;
    }

    __shared__ float Yr[kL - 1][2][kChunk][kYW];  // 32 KB, padded rows
    __shared__ float XW0[kChunk][kG];             // 3 KB, fallback only
    __shared__ float hfin[kH];

    const int wid = tid >> 6, lane = tid & 63;
    const int g = (lane < kG) ? lane : (kG - 1);
    const bool fast = (b < qmax);
    const float* xgb = xg0 + (size_t)b * kT * kG + g;
    const float sc = (g < 32) ? kLog2e : 2.0f * kLog2e;   // exp2 row folding

    float wreg[kH], wih[kH];
    float bh, bi = 0.f, h = 0.f;
    {
        const float* wrow = Whh + (size_t)(wid * kG + g) * kH;
        #pragma unroll
        for (int k = 0; k < kH; ++k) wreg[k] = wrow[k] * sc;
        bh = bhh[wid * kG + g] * sc;
        if (wid > 0) {
            const float* wr2 = Wihr + (size_t)((wid - 1) * kG + g) * kH;
            #pragma unroll
            for (int k = 0; k < kH; ++k) wih[k] = wr2[k] * sc;
            bi = bih[wid * kG + g] * sc;
        } else {
            #pragma unroll
            for (int k = 0; k < kH; ++k) wih[k] = 0.f;
        }
    }

    float xgr[kChunk];
    // ---- preload chunk 0 into wave-0 registers ----
    if (wid == 0) {
        if (fast) {
            #pragma unroll
            for (int tt = 0; tt < kChunk; ++tt) xgr[tt] = xgb[(size_t)tt * kG];
        } else {
            proj_chunk_wave0(x, Wih0, bih, b, 0, lane, XW0);
            asm volatile("s_waitcnt lgkmcnt(0)" ::: "memory");
            #pragma unroll
            for (int tt = 0; tt < kChunk; ++tt) xgr[tt] = XW0[tt][g];
        }
    }

    // ---- lag-2 wavefront: wave l scans chunk c = p - 2l ----
    for (int p = 0; p < kPhases; ++p) {
        const int c = p - 2 * wid;
        const bool sc_ = (c >= 0 && c < kNC);
        const bool pr = (c + 1 >= 0 && c + 1 < kNC);
        if (wid == 0) {
            float (*yo)[kYW] = Yr[0][c & 1];
            if (fast) {
                const float* gsrc = xgb + (size_t)(c + 1) * kChunk * kG;
                if (sc_ && pr)
                    h = phase_body<true, 1, true>(h, xgr, gsrc, nullptr, yo, wreg, bh, wih, bi, lane);
                else if (sc_)
                    h = phase_body<true, 0, true>(h, xgr, nullptr, nullptr, yo, wreg, bh, wih, bi, lane);
            } else {
                if (sc_)
                    h = phase_body<true, 0, true>(h, xgr, nullptr, nullptr, yo, wreg, bh, wih, bi, lane);
                if (pr) {
                    proj_chunk_wave0(x, Wih0, bih, b, c + 1, lane, XW0);
                    asm volatile("s_waitcnt lgkmcnt(0)" ::: "memory");
                    #pragma unroll
                    for (int tt = 0; tt < kChunk; ++tt) xgr[tt] = XW0[tt][g];
                }
            }
        } else {
            const float (*yp)[kYW] = Yr[wid - 1][(c + 1) & 1];
            float (*yo)[kYW] = Yr[(wid < kL - 1) ? wid : 0][c & 1];  // dummy if !WY
            if (wid < kL - 1) {
                if (sc_ && pr)
                    h = phase_body<true, 2, true>(h, xgr, nullptr, yp, yo, wreg, bh, wih, bi, lane);
                else if (sc_)
                    h = phase_body<true, 0, true>(h, xgr, nullptr, yp, yo, wreg, bh, wih, bi, lane);
                else if (pr)
                    h = phase_body<false, 2, false>(h, xgr, nullptr, yp, yo, wreg, bh, wih, bi, lane);
            } else {
                if (sc_ && pr)
                    h = phase_body<true, 2, false>(h, xgr, nullptr, yp, yo, wreg, bh, wih, bi, lane);
                else if (sc_)
                    h = phase_body<true, 0, false>(h, xgr, nullptr, yp, yo, wreg, bh, wih, bi, lane);
                else if (pr)
                    h = phase_body<false, 2, false>(h, xgr, nullptr, yp, yo, wreg, bh, wih, bi, lane);
            }
        }
        barrier_lgkm();   // lgkm-only: wave-0 global prefetch stays in flight
    }

    if (wid == kL - 1 && lane < kH) hfin[lane] = h;
    __syncthreads();

    if (tid < kC) {
        float acc = bfc[tid];
        #pragma unroll
        for (int j = 0; j < kH; ++j)
            acc = fmaf(hfin[j], Wfc[tid * kH + j], acc);
        out[b * kC + tid] = acc;
    }
}

extern "C" void kernel_launch(void* const* d_in, const int* in_sizes, int n_in,
                              void* d_out, int out_size, void* d_ws, size_t ws_size,
                              hipStream_t stream) {
    const float* x    = (const float*)d_in[0];
    const int*   len  = (const int*)d_in[1];
    const float* Wih0 = (const float*)d_in[2];
    const float* Wihr = (const float*)d_in[3];
    const float* Whh  = (const float*)d_in[4];
    const float* bih  = (const float*)d_in[5];
    const float* bhh  = (const float*)d_in[6];
    const float* Wfc  = (const float*)d_in[7];
    const float* bfc  = (const float*)d_in[8];
    float* outp = (float*)d_out;
    float* xg0  = (float*)d_ws;

    size_t per_row = (size_t)kT * kG * sizeof(float);
    int qmax = (int)((ws_size / per_row) < (size_t)kB ? (ws_size / per_row) : (size_t)kB);

    hipLaunchKernelGGL(proj0, dim3(kB), dim3(256), 0, stream,
                       x, len, Wih0, bih, xg0, qmax);
    hipLaunchKernelGGL(gru_pipe4, dim3(kB), dim3(kThreads), 0, stream,
                       x, len, Wih0, Wihr, Whh, bih, bhh, Wfc, bfc, xg0, outp, qmax);
}

// Round 6
// 181.119 us; speedup vs baseline: 3.1663x; 3.1663x over previous
//
#include <hip/hip_runtime.h>

// 5-layer GRU (H=16), T=512; only rows with length==T matter (~2 of 512, a
// PREFIX since lengths sorted descending). proj0 precomputes layer-0 xg.
// R6: R5's chain-optimized pipe (exp2 weight folding, n-gate on r-lanes,
// yprev register prefetch, chunk=16) + R4's PARALLEL proj0 tiling (16 tiles
// of 32 t per row; R5's 1-block-per-row proj0 was a 455us latency bottleneck).

constexpr int kB = 512, kT = 512, kD = 128, kH = 16, kL = 5, kC = 2, kG = 48;
constexpr int kChunk = 16, kNC = kT / kChunk, kThreads = 320;
constexpr int kPhases = kNC + 2 * (kL - 1);
constexpr int kYW = 64;   // padded Y row: all 64 lanes write, [16..63] is pad
constexpr float kLog2e = 1.4426950408889634f;

typedef unsigned uint2v __attribute__((ext_vector_type(2)));

__device__ __forceinline__ float rl(float v, int lane) {
    return __int_as_float(__builtin_amdgcn_readlane(__float_as_int(v), lane));
}

__device__ __forceinline__ float fexp2(float x) {
#if __has_builtin(__builtin_amdgcn_exp2f)
    return __builtin_amdgcn_exp2f(x);
#else
    return exp2f(x);
#endif
}

#if __has_builtin(__builtin_amdgcn_permlane32_swap) && __has_builtin(__builtin_amdgcn_permlane16_swap)
// Direction-agnostic partner select (absmax 0 across R2-R5 -> proven form).
__device__ __forceinline__ float sel_other(uint2v r, float self) {
    unsigned s = __float_as_uint(self);
    return __uint_as_float((r[0] == s) ? r[1] : r[0]);
}
__device__ __forceinline__ float xor32(float v) {
    uint2v r = __builtin_amdgcn_permlane32_swap(__float_as_uint(v), __float_as_uint(v), false, false);
    return sel_other(r, v);
}
__device__ __forceinline__ float xor16(float v) {
    uint2v r = __builtin_amdgcn_permlane16_swap(__float_as_uint(v), __float_as_uint(v), false, false);
    return sel_other(r, v);
}
#else
__device__ __forceinline__ float bperm_xor(float v, int xmask) {
    int lane = threadIdx.x & 63;
    return __int_as_float(__builtin_amdgcn_ds_bpermute((lane ^ xmask) * 4, __float_as_int(v)));
}
__device__ __forceinline__ float xor32(float v) { return bperm_xor(v, 32); }
__device__ __forceinline__ float xor16(float v) { return bperm_xor(v, 16); }
#endif

// One GRU step. Lane g owns gate-row g (r:0-15, z:16-31, n:32-47); h in lanes
// 0-15. Weights/xg pre-scaled: rows<32 by log2e, rows>=32 by 2*log2e, so
// sigmoid = rcp(1+exp2(-s)) and tanh needs no argument multiply.
// n is evaluated ON the r-lanes (hg/xg swapped across the 32 boundary early,
// off the critical chain), so no swap sits between sigmoid and tanh.
__device__ __forceinline__ float gru_step(float h, float xg,
                                          const float (&wreg)[kH], float bh) {
    float a0 = bh, a1 = 0.f, a2 = 0.f, a3 = 0.f;
    #pragma unroll
    for (int k = 0; k < 4; ++k) {
        a0 = fmaf(rl(h, k),      wreg[k],      a0);
        a1 = fmaf(rl(h, k + 4),  wreg[k + 4],  a1);
        a2 = fmaf(rl(h, k + 8),  wreg[k + 8],  a2);
        a3 = fmaf(rl(h, k + 12), wreg[k + 12], a3);
    }
    float xnb = xor32(xg);                    // lanes<16 get xn' (off-chain)
    float hg = (a0 + a1) + (a2 + a3);
    float hnb = xor32(hg);                    // lanes<16 get hn' (off-chain)
    float s = xg + hg;                        // log2e-scaled for r/z lanes
    float sig = __builtin_amdgcn_rcpf(1.0f + fexp2(-s));   // r:0-15, z:16-31
    float zb = xor16(sig);                    // lanes<16 get z (|| tanh chain)
    float narg = fmaf(sig, hnb, xnb);         // lanes<16: 2log2e*(xn + r*hn)
    float nv = fmaf(-2.0f, __builtin_amdgcn_rcpf(fexp2(narg) + 1.0f), 1.0f);
    return fmaf(zb, h - nv, nv);              // h' = n + z*(h-n), lanes 0-15
}

// Fused phase over one chunk: scan chunk c from xgr while preparing chunk
// c+1's xg in-place. PREP: 0 none, 1 global load (wave 0), 2 project from
// prev layer's Y with one-step register prefetch of the Y row.
template<bool SCAN, int PREP, bool WY>
__device__ __forceinline__ float phase_body(
    float h, float (&xgr)[kChunk], const float* __restrict__ gsrc,
    const float (*__restrict__ yprev)[kYW], float (*__restrict__ yout)[kYW],
    const float (&wreg)[kH], float bh, const float (&wih)[kH], float bi,
    int lane)
{
    float4 ra0, ra1, ra2, ra3;
    if (PREP == 2) {                           // prefetch row 0
        const float4* y4 = (const float4*)&yprev[0][0];
        ra0 = y4[0]; ra1 = y4[1]; ra2 = y4[2]; ra3 = y4[3];
    }
    #pragma unroll
    for (int tt = 0; tt < kChunk; ++tt) {
        float4 rb0 = ra0, rb1 = ra1, rb2 = ra2, rb3 = ra3;
        if (PREP == 2 && tt + 1 < kChunk) {    // issue next row's loads early
            const float4* y4 = (const float4*)&yprev[tt + 1][0];
            rb0 = y4[0]; rb1 = y4[1]; rb2 = y4[2]; rb3 = y4[3];
        }
        if (SCAN) {
            h = gru_step(h, xgr[tt], wreg, bh);
            if (WY) yout[tt][lane] = h;        // unconditional; pad absorbs 16-63
        }
        if (PREP == 1) {
            xgr[tt] = gsrc[(size_t)tt * kG];
        } else if (PREP == 2) {
            float p0 = bi, p1 = 0.f, p2 = 0.f, p3 = 0.f;   // dot uses regs (ra)
            p0 = fmaf(ra0.x, wih[0],  p0); p0 = fmaf(ra0.y, wih[1],  p0);
            p0 = fmaf(ra0.z, wih[2],  p0); p0 = fmaf(ra0.w, wih[3],  p0);
            p1 = fmaf(ra1.x, wih[4],  p1); p1 = fmaf(ra1.y, wih[5],  p1);
            p1 = fmaf(ra1.z, wih[6],  p1); p1 = fmaf(ra1.w, wih[7],  p1);
            p2 = fmaf(ra2.x, wih[8],  p2); p2 = fmaf(ra2.y, wih[9],  p2);
            p2 = fmaf(ra2.z, wih[10], p2); p2 = fmaf(ra2.w, wih[11], p2);
            p3 = fmaf(ra3.x, wih[12], p3); p3 = fmaf(ra3.y, wih[13], p3);
            p3 = fmaf(ra3.z, wih[14], p3); p3 = fmaf(ra3.w, wih[15], p3);
            xgr[tt] = (p0 + p1) + (p2 + p3);
            ra0 = rb0; ra1 = rb1; ra2 = rb2; ra3 = rb3;    // SSA-renamed away
        }
    }
    return h;
}

// ---- prologue: xg0[b][t][g] = scale(g)*(b_ih[g] + W_ih0[g,:].x[b,t,:]) ----
// 16 tiles of 32 t per row -> only ~32 blocks active but they spread across
// CUs (R4-proven config; 1-block-per-row variant was a 455us bottleneck).
extern "C" __global__ void __launch_bounds__(256, 1)
proj0(const float* __restrict__ x, const int* __restrict__ len,
      const float* __restrict__ Wih0, const float* __restrict__ bih,
      float* __restrict__ xg0, int qmax)
{
    const int blk = blockIdx.x;
    const int b = blk >> 4, s = blk & 15;       // 16 tiles of 32 t per row
    if (b >= qmax || len[b] != kT) return;
    const int tid = threadIdx.x;
    #pragma unroll
    for (int i = 0; i < 6; ++i) {
        int item = tid + 256 * i;               // item = t*48+g
        int t = item / kG, g = item - t * kG;
        const float4* xr = (const float4*)(x + ((size_t)b * kT + s * 32 + t) * kD);
        const float4* wr = (const float4*)(Wih0 + (size_t)g * kD);
        float a0 = 0.f, a1 = 0.f, a2 = 0.f, a3 = 0.f;
        #pragma unroll 8
        for (int k = 0; k < kD / 4; ++k) {
            float4 xv = xr[k], wv = wr[k];
            a0 = fmaf(xv.x, wv.x, a0);
            a1 = fmaf(xv.y, wv.y, a1);
            a2 = fmaf(xv.z, wv.z, a2);
            a3 = fmaf(xv.w, wv.w, a3);
        }
        float scg = (g < 32) ? kLog2e : 2.0f * kLog2e;
        xg0[((size_t)b * kT + s * 32 + t) * kG + g] =
            scg * (bih[g] + ((a0 + a1) + (a2 + a3)));
    }
}

// Fallback (ws too small for this row): wave 0 computes one chunk from x.
__device__ void proj_chunk_wave0(const float* __restrict__ x,
                                 const float* __restrict__ Wih0,
                                 const float* __restrict__ bih,
                                 int b, int c, int lane, float (*__restrict__ XW0)[kG])
{
    for (int i = 0; i < kChunk * kG / 64; ++i) {
        int item = lane + 64 * i;
        int t = item / kG, g = item - t * kG;
        const float4* xr = (const float4*)(x + ((size_t)b * kT + c * kChunk + t) * kD);
        const float4* wr = (const float4*)(Wih0 + (size_t)g * kD);
        float a0 = 0.f, a1 = 0.f, a2 = 0.f, a3 = 0.f;
        #pragma unroll 8
        for (int k = 0; k < kD / 4; ++k) {
            float4 xv = xr[k], wv = wr[k];
            a0 = fmaf(xv.x, wv.x, a0);
            a1 = fmaf(xv.y, wv.y, a1);
            a2 = fmaf(xv.z, wv.z, a2);
            a3 = fmaf(xv.w, wv.w, a3);
        }
        float scg = (g < 32) ? kLog2e : 2.0f * kLog2e;
        XW0[t][g] = scg * (bih[g] + ((a0 + a1) + (a2 + a3)));
    }
}

__device__ __forceinline__ void barrier_lgkm() {
    asm volatile("s_waitcnt lgkmcnt(0)" ::: "memory");
    __builtin_amdgcn_s_barrier();
}

extern "C" __global__ void __launch_bounds__(kThreads, 1)
gru_pipe4(const float* __restrict__ x, const int* __restrict__ len,
          const float* __restrict__ Wih0, const float* __restrict__ Wihr,
          const float* __restrict__ Whh, const float* __restrict__ bih,
          const float* __restrict__ bhh, const float* __restrict__ Wfc,
          const float* __restrict__ bfc, const float* __restrict__ xg0,
          float* __restrict__ out, int qmax)
{
    const int b = blockIdx.x;
    const int tid = threadIdx.x;

    if (len[b] != kT) {                 // uniform: output is just b_fc
        if (tid < kC) out[b * kC + tid] = bfc[tid];
        return;
    }

    __shared__ float Yr[kL - 1][2][kChunk][kYW];  // 32 KB, padded rows
    __shared__ float XW0[kChunk][kG];             // 3 KB, fallback only
    __shared__ float hfin[kH];

    const int wid = tid >> 6, lane = tid & 63;
    const int g = (lane < kG) ? lane : (kG - 1);
    const bool fast = (b < qmax);
    const float* xgb = xg0 + (size_t)b * kT * kG + g;
    const float sc = (g < 32) ? kLog2e : 2.0f * kLog2e;   // exp2 row folding

    float wreg[kH], wih[kH];
    float bh, bi = 0.f, h = 0.f;
    {
        const float* wrow = Whh + (size_t)(wid * kG + g) * kH;
        #pragma unroll
        for (int k = 0; k < kH; ++k) wreg[k] = wrow[k] * sc;
        bh = bhh[wid * kG + g] * sc;
        if (wid > 0) {
            const float* wr2 = Wihr + (size_t)((wid - 1) * kG + g) * kH;
            #pragma unroll
            for (int k = 0; k < kH; ++k) wih[k] = wr2[k] * sc;
            bi = bih[wid * kG + g] * sc;
        } else {
            #pragma unroll
            for (int k = 0; k < kH; ++k) wih[k] = 0.f;
        }
    }

    float xgr[kChunk];
    // ---- preload chunk 0 into wave-0 registers ----
    if (wid == 0) {
        if (fast) {
            #pragma unroll
            for (int tt = 0; tt < kChunk; ++tt) xgr[tt] = xgb[(size_t)tt * kG];
        } else {
            proj_chunk_wave0(x, Wih0, bih, b, 0, lane, XW0);
            asm volatile("s_waitcnt lgkmcnt(0)" ::: "memory");
            #pragma unroll
            for (int tt = 0; tt < kChunk; ++tt) xgr[tt] = XW0[tt][g];
        }
    }

    // ---- lag-2 wavefront: wave l scans chunk c = p - 2l ----
    for (int p = 0; p < kPhases; ++p) {
        const int c = p - 2 * wid;
        const bool sc_ = (c >= 0 && c < kNC);
        const bool pr = (c + 1 >= 0 && c + 1 < kNC);
        if (wid == 0) {
            float (*yo)[kYW] = Yr[0][c & 1];
            if (fast) {
                const float* gsrc = xgb + (size_t)(c + 1) * kChunk * kG;
                if (sc_ && pr)
                    h = phase_body<true, 1, true>(h, xgr, gsrc, nullptr, yo, wreg, bh, wih, bi, lane);
                else if (sc_)
                    h = phase_body<true, 0, true>(h, xgr, nullptr, nullptr, yo, wreg, bh, wih, bi, lane);
            } else {
                if (sc_)
                    h = phase_body<true, 0, true>(h, xgr, nullptr, nullptr, yo, wreg, bh, wih, bi, lane);
                if (pr) {
                    proj_chunk_wave0(x, Wih0, bih, b, c + 1, lane, XW0);
                    asm volatile("s_waitcnt lgkmcnt(0)" ::: "memory");
                    #pragma unroll
                    for (int tt = 0; tt < kChunk; ++tt) xgr[tt] = XW0[tt][g];
                }
            }
        } else {
            const float (*yp)[kYW] = Yr[wid - 1][(c + 1) & 1];
            float (*yo)[kYW] = Yr[(wid < kL - 1) ? wid : 0][c & 1];  // dummy if !WY
            if (wid < kL - 1) {
                if (sc_ && pr)
                    h = phase_body<true, 2, true>(h, xgr, nullptr, yp, yo, wreg, bh, wih, bi, lane);
                else if (sc_)
                    h = phase_body<true, 0, true>(h, xgr, nullptr, yp, yo, wreg, bh, wih, bi, lane);
                else if (pr)
                    h = phase_body<false, 2, false>(h, xgr, nullptr, yp, yo, wreg, bh, wih, bi, lane);
            } else {
                if (sc_ && pr)
                    h = phase_body<true, 2, false>(h, xgr, nullptr, yp, yo, wreg, bh, wih, bi, lane);
                else if (sc_)
                    h = phase_body<true, 0, false>(h, xgr, nullptr, yp, yo, wreg, bh, wih, bi, lane);
                else if (pr)
                    h = phase_body<false, 2, false>(h, xgr, nullptr, yp, yo, wreg, bh, wih, bi, lane);
            }
        }
        barrier_lgkm();   // lgkm-only: wave-0 global prefetch stays in flight
    }

    if (wid == kL - 1 && lane < kH) hfin[lane] = h;
    __syncthreads();

    if (tid < kC) {
        float acc = bfc[tid];
        #pragma unroll
        for (int j = 0; j < kH; ++j)
            acc = fmaf(hfin[j], Wfc[tid * kH + j], acc);
        out[b * kC + tid] = acc;
    }
}

extern "C" void kernel_launch(void* const* d_in, const int* in_sizes, int n_in,
                              void* d_out, int out_size, void* d_ws, size_t ws_size,
                              hipStream_t stream) {
    const float* x    = (const float*)d_in[0];
    const int*   len  = (const int*)d_in[1];
    const float* Wih0 = (const float*)d_in[2];
    const float* Wihr = (const float*)d_in[3];
    const float* Whh  = (const float*)d_in[4];
    const float* bih  = (const float*)d_in[5];
    const float* bhh  = (const float*)d_in[6];
    const float* Wfc  = (const float*)d_in[7];
    const float* bfc  = (const float*)d_in[8];
    float* outp = (float*)d_out;
    float* xg0  = (float*)d_ws;

    size_t per_row = (size_t)kT * kG * sizeof(float);
    int qmax = (int)((ws_size / per_row) < (size_t)kB ? (ws_size / per_row) : (size_t)kB);

    hipLaunchKernelGGL(proj0, dim3(kB * 16), dim3(256), 0, stream,
                       x, len, Wih0, bih, xg0, qmax);
    hipLaunchKernelGGL(gru_pipe4, dim3(kB), dim3(kThreads), 0, stream,
                       x, len, Wih0, Wihr, Whh, bih, bhh, Wfc, bfc, xg0, outp, qmax);
}